// Round 5
// baseline (84.632 us; speedup 1.0000x reference)
//
#include <hip/hip_runtime.h>
#include <math.h>

// SSIM loss, fused separable 11x11 Gaussian conv + SSIM map + mean.
// Images: 32 x 1 x 512 x 512 fp32. Output: 1 fp32 scalar.
//
// R5: 4-field algebra. SSIM needs only (sigma1+sigma2), so with p=a+b,
// m=a-b:  conv(p^2)+conv(m^2) = 2(E[a2]+E[b2]),  conv(p^2)-conv(m^2) = 4E[ab].
// => convolve {a, b, p^2, m^2}: 4 convs instead of 5 (-20% FMA both passes).
// LDS: hAB=(conv a, conv b) bf16-pair u32 [74][32], hPM=(conv p2, conv m2)
// u32 [74][32] = 19 KB. Stage-3 LDS reads 54 -> 36 per thread.
// Stage 2 uses 8-wide tasks: 10 global loads per 8 outputs (was 16).
//
// Tile: 64 rows x 32 cols per 256-thread block.
// Stage 2: horizontal Gaussian direct from global -> packed LDS
// Stage 3: vertical Gaussian in registers -> SSIM -> block partial sum
// Kernel 2: deterministic tree reduce of 4096 partials -> scalar.

#define IMGW 512
#define IMGH 512
#define NIMG 32
#define TW 32
#define TH 64
#define IN_H 74        // TH + 10
#define NBX 16         // 512 / TW
#define NBY 8          // 512 / TH
#define NBLOCKS (NBX * NBY * NIMG)   // 4096

// Unaligned-tolerant vectors (dword-aligned global loads).
typedef float float4u __attribute__((ext_vector_type(4), aligned(4)));
typedef float float2u __attribute__((ext_vector_type(2), aligned(4)));

__device__ __forceinline__ uint32_t pkbf(float lo, float hi) {
  uint32_t a = __builtin_bit_cast(uint32_t, lo);
  uint32_t b = __builtin_bit_cast(uint32_t, hi);
  return (a >> 16) | (b & 0xffff0000u);
}
__device__ __forceinline__ float up_lo(uint32_t w) {
  return __builtin_bit_cast(float, w << 16);
}
__device__ __forceinline__ float up_hi(uint32_t w) {
  return __builtin_bit_cast(float, w & 0xffff0000u);
}

__global__ __launch_bounds__(256, 4) void ssim_main(
    const float* __restrict__ img1, const float* __restrict__ img2,
    float* __restrict__ partial) {
  __shared__ uint32_t hAB[IN_H][TW];   // (conv a, conv b)
  __shared__ uint32_t hPM[IN_H][TW];   // (conv p^2, conv m^2)
  __shared__ float sWave[4];

  // Unnormalized Gaussian, 2*sigma^2 = 4 (faithful to reference).
  constexpr float g[11] = {0.0019304541f, 0.018315639f, 0.10539922f,
                           0.36787944f,   0.7788008f,   1.0f,
                           0.7788008f,    0.36787944f,  0.10539922f,
                           0.018315639f,  0.0019304541f};
  constexpr float C1v = 6.5025f;    // (0.01*255)^2
  constexpr float C2v = 58.5225f;   // (0.03*255)^2

  const int tid = threadIdx.x;
  const int bx = blockIdx.x;
  const int by = blockIdx.y;
  const int x0 = bx * TW - 5;
  const int y0 = by * TH - 5;
  const float* __restrict__ p1 = img1 + (size_t)blockIdx.z * (IMGW * IMGH);
  const float* __restrict__ p2 = img2 + (size_t)blockIdx.z * (IMGW * IMGH);
  const bool interior = (bx >= 1) && (bx <= NBX - 2) && (by >= 1) && (by <= NBY - 2);

  // ---- Stage 2: horizontal pass, direct global reads, 8 outputs/task ----
  // tasks: 74 rows x 4 col-groups = 296
  for (int idx = tid; idx < IN_H * (TW / 8); idx += 256) {
    int r = idx >> 2;
    int c0 = (idx & 3) << 3;
    int gy = y0 + r;
    int gxw = x0 + c0;  // window covers global cols [gxw, gxw+17]
    float av[18], bv[18];
    if (interior) {
      const float* r1 = p1 + gy * IMGW + gxw;
      const float* r2 = p2 + gy * IMGW + gxw;
      float4u A0 = *(const float4u*)(r1);
      float4u A1 = *(const float4u*)(r1 + 4);
      float4u A2 = *(const float4u*)(r1 + 8);
      float4u A3 = *(const float4u*)(r1 + 12);
      float2u A4 = *(const float2u*)(r1 + 16);
      float4u B0 = *(const float4u*)(r2);
      float4u B1 = *(const float4u*)(r2 + 4);
      float4u B2 = *(const float4u*)(r2 + 8);
      float4u B3 = *(const float4u*)(r2 + 12);
      float2u B4 = *(const float2u*)(r2 + 16);
#pragma unroll
      for (int i = 0; i < 4; ++i) {
        av[i] = A0[i]; av[4 + i] = A1[i]; av[8 + i] = A2[i]; av[12 + i] = A3[i];
        bv[i] = B0[i]; bv[4 + i] = B1[i]; bv[8 + i] = B2[i]; bv[12 + i] = B3[i];
      }
      av[16] = A4[0]; av[17] = A4[1];
      bv[16] = B4[0]; bv[17] = B4[1];
    } else {
      bool rowok = (gy >= 0) && (gy < IMGH);
      const float* r1 = p1 + gy * IMGW;
      const float* r2 = p2 + gy * IMGW;
#pragma unroll
      for (int i = 0; i < 18; ++i) {
        int gx = gxw + i;
        bool ok = rowok && (gx >= 0) && (gx < IMGW);
        av[i] = ok ? r1[gx] : 0.0f;
        bv[i] = ok ? r2[gx] : 0.0f;
      }
    }
    float pv[18], mv[18];
#pragma unroll
    for (int k = 0; k < 18; ++k) {
      float p = av[k] + bv[k];
      float m = av[k] - bv[k];
      pv[k] = p * p;
      mv[k] = m * m;
    }
    float sa[8], sb[8], sp[8], sm[8];
#pragma unroll
    for (int o = 0; o < 8; ++o) {
      float ta = 0.f, tb = 0.f, tp = 0.f, tm = 0.f;
#pragma unroll
      for (int k = 0; k < 11; ++k) {
        float w = g[k];
        ta = fmaf(w, av[o + k], ta);
        tb = fmaf(w, bv[o + k], tb);
        tp = fmaf(w, pv[o + k], tp);
        tm = fmaf(w, mv[o + k], tm);
      }
      sa[o] = ta; sb[o] = tb; sp[o] = tp; sm[o] = tm;
    }
    uint4 wab0, wab1, wpm0, wpm1;
    wab0.x = pkbf(sa[0], sb[0]); wab0.y = pkbf(sa[1], sb[1]);
    wab0.z = pkbf(sa[2], sb[2]); wab0.w = pkbf(sa[3], sb[3]);
    wab1.x = pkbf(sa[4], sb[4]); wab1.y = pkbf(sa[5], sb[5]);
    wab1.z = pkbf(sa[6], sb[6]); wab1.w = pkbf(sa[7], sb[7]);
    wpm0.x = pkbf(sp[0], sm[0]); wpm0.y = pkbf(sp[1], sm[1]);
    wpm0.z = pkbf(sp[2], sm[2]); wpm0.w = pkbf(sp[3], sm[3]);
    wpm1.x = pkbf(sp[4], sm[4]); wpm1.y = pkbf(sp[5], sm[5]);
    wpm1.z = pkbf(sp[6], sm[6]); wpm1.w = pkbf(sp[7], sm[7]);
    *(uint4*)&hAB[r][c0] = wab0;
    *(uint4*)&hAB[r][c0 + 4] = wab1;
    *(uint4*)&hPM[r][c0] = wpm0;
    *(uint4*)&hPM[r][c0 + 4] = wpm1;
  }
  __syncthreads();

  // ---- Stage 3: vertical pass in registers, 8 output rows per thread ----
  const int c = tid & 31;
  const int r0 = (tid >> 5) << 3;  // 0..56
  float mu1[8], mu2[8], qp[8], qm[8];
  {
    float m1[18], m2[18];
#pragma unroll
    for (int k = 0; k < 18; ++k) {
      uint32_t w = hAB[r0 + k][c];
      m1[k] = up_lo(w);
      m2[k] = up_hi(w);
    }
#pragma unroll
    for (int o = 0; o < 8; ++o) {
      float s = 0.f, t = 0.f;
#pragma unroll
      for (int k = 0; k < 11; ++k) {
        s = fmaf(g[k], m1[o + k], s);
        t = fmaf(g[k], m2[o + k], t);
      }
      mu1[o] = s; mu2[o] = t;
    }
#pragma unroll
    for (int k = 0; k < 18; ++k) {
      uint32_t w = hPM[r0 + k][c];
      m1[k] = up_lo(w);
      m2[k] = up_hi(w);
    }
#pragma unroll
    for (int o = 0; o < 8; ++o) {
      float s = 0.f, t = 0.f;
#pragma unroll
      for (int k = 0; k < 11; ++k) {
        s = fmaf(g[k], m1[o + k], s);
        t = fmaf(g[k], m2[o + k], t);
      }
      qp[o] = s; qm[o] = t;
    }
  }

  float ssum = 0.f;
#pragma unroll
  for (int o = 0; o < 8; ++o) {
    float m1 = mu1[o], m2 = mu2[o];
    float sumsq = 0.5f * (qp[o] + qm[o]);   // E[a^2] + E[b^2]
    float eab = 0.25f * (qp[o] - qm[o]);    // E[ab]
    float m1s = m1 * m1, m2s = m2 * m2, m12 = m1 * m2;
    float sg12 = eab - m12;
    float sgsum = sumsq - m1s - m2s;        // sigma1 + sigma2
    float num = (2.0f * m12 + C1v) * (2.0f * sg12 + C2v);
    float den = (m1s + m2s + C1v) * (sgsum + C2v);
    float r = num * __builtin_amdgcn_rcpf(den);
    // Guard singular pixels (den rounds to +-0 -> inf; mixed-sign infs -> NaN).
    if (!__builtin_isfinite(r)) r = 0.0f;
    ssum += r;
  }

  // ---- block reduction (deterministic) ----
#pragma unroll
  for (int off = 32; off > 0; off >>= 1) ssum += __shfl_down(ssum, off, 64);
  if ((tid & 63) == 0) sWave[tid >> 6] = ssum;
  __syncthreads();
  if (tid == 0) {
    partial[(blockIdx.z * NBY + blockIdx.y) * NBX + blockIdx.x] =
        sWave[0] + sWave[1] + sWave[2] + sWave[3];
  }
}

__global__ __launch_bounds__(256) void ssim_reduce(
    const float* __restrict__ partial, float* __restrict__ out) {
  const int tid = threadIdx.x;
  float s = 0.f;
  for (int i = tid; i < NBLOCKS; i += 256) s += partial[i];
#pragma unroll
  for (int off = 32; off > 0; off >>= 1) s += __shfl_down(s, off, 64);
  __shared__ float sw[4];
  if ((tid & 63) == 0) sw[tid >> 6] = s;
  __syncthreads();
  if (tid == 0) {
    float tot = sw[0] + sw[1] + sw[2] + sw[3];
    // mean((1 - ssim)/2) = 0.5 * (1 - mean(ssim))
    float val = 0.5f * (1.0f - tot * (1.0f / (32.0f * 512.0f * 512.0f)));
    if (!__builtin_isfinite(val)) val = 0.0f;
    out[0] = val;
  }
}

extern "C" void kernel_launch(void* const* d_in, const int* in_sizes, int n_in,
                              void* d_out, int out_size, void* d_ws,
                              size_t ws_size, hipStream_t stream) {
  const float* img1 = (const float*)d_in[0];
  const float* img2 = (const float*)d_in[1];
  float* partial = (float*)d_ws;  // 4096 floats = 16 KB
  float* out = (float*)d_out;

  dim3 grid(NBX, NBY, NIMG);
  hipLaunchKernelGGL(ssim_main, grid, dim3(256), 0, stream, img1, img2,
                     partial);
  hipLaunchKernelGGL(ssim_reduce, dim3(1), dim3(256), 0, stream, partial, out);
}

// Round 6
// 74.017 us; speedup vs baseline: 1.1434x; 1.1434x over previous
//
#include <hip/hip_runtime.h>
#include <math.h>

// SSIM loss, fused separable 11x11 Gaussian conv + SSIM map + mean.
// Images: 32 x 1 x 512 x 512 fp32. Output: 1 fp32 scalar.
//
// R6 = R5 algebra + R4 geometry + R4 occupancy.
// 4-field algebra: p=a+b, m=a-b; conv{a,b,p^2,m^2};
//   E[a2]+E[b2] = (cp+cm)/2, E[ab] = (cp-cm)/4.
// Stage 2: 4-wide tasks (74 rows x 8 groups = 592, 77% slot util),
//   14-float windows: 3x dwordx4 + 1x dwordx2 per image.
// LDS: hAB=(ca,cb) bf16-pair u32 [74][32]; hPM=(cp2,cm2) u32 [74][32] = 19KB.
// launch_bounds(256,6) -> 6 blocks/CU (24 waves).
//
// Stage 3: vertical Gaussian in registers -> SSIM -> block partial sum
// Kernel 2: deterministic tree reduce of 4096 partials -> scalar.

#define IMGW 512
#define IMGH 512
#define NIMG 32
#define TW 32
#define TH 64
#define IN_H 74        // TH + 10
#define NBX 16         // 512 / TW
#define NBY 8          // 512 / TH
#define NBLOCKS (NBX * NBY * NIMG)   // 4096

// Unaligned-tolerant vectors (dword-aligned global loads).
typedef float float4u __attribute__((ext_vector_type(4), aligned(4)));
typedef float float2u __attribute__((ext_vector_type(2), aligned(4)));

__device__ __forceinline__ uint32_t pkbf(float lo, float hi) {
  uint32_t a = __builtin_bit_cast(uint32_t, lo);
  uint32_t b = __builtin_bit_cast(uint32_t, hi);
  return (a >> 16) | (b & 0xffff0000u);
}
__device__ __forceinline__ float up_lo(uint32_t w) {
  return __builtin_bit_cast(float, w << 16);
}
__device__ __forceinline__ float up_hi(uint32_t w) {
  return __builtin_bit_cast(float, w & 0xffff0000u);
}

__global__ __launch_bounds__(256, 6) void ssim_main(
    const float* __restrict__ img1, const float* __restrict__ img2,
    float* __restrict__ partial) {
  __shared__ uint32_t hAB[IN_H][TW];   // (conv a, conv b)
  __shared__ uint32_t hPM[IN_H][TW];   // (conv p^2, conv m^2)
  __shared__ float sWave[4];

  // Unnormalized Gaussian, 2*sigma^2 = 4 (faithful to reference).
  constexpr float g[11] = {0.0019304541f, 0.018315639f, 0.10539922f,
                           0.36787944f,   0.7788008f,   1.0f,
                           0.7788008f,    0.36787944f,  0.10539922f,
                           0.018315639f,  0.0019304541f};
  constexpr float C1v = 6.5025f;    // (0.01*255)^2
  constexpr float C2v = 58.5225f;   // (0.03*255)^2

  const int tid = threadIdx.x;
  const int bx = blockIdx.x;
  const int by = blockIdx.y;
  const int x0 = bx * TW - 5;
  const int y0 = by * TH - 5;
  const float* __restrict__ p1 = img1 + (size_t)blockIdx.z * (IMGW * IMGH);
  const float* __restrict__ p2 = img2 + (size_t)blockIdx.z * (IMGW * IMGH);
  const bool interior = (bx >= 1) && (bx <= NBX - 2) && (by >= 1) && (by <= NBY - 2);

  // ---- Stage 2: horizontal pass, direct global reads, 4 outputs/task ----
  // tasks: 74 rows x 8 col-groups = 592
  for (int idx = tid; idx < IN_H * (TW / 4); idx += 256) {
    int r = idx >> 3;
    int c0 = (idx & 7) << 2;
    int gy = y0 + r;
    int gxw = x0 + c0;  // window covers global cols [gxw, gxw+13]
    float av[14], bv[14];
    if (interior) {
      const float* r1 = p1 + gy * IMGW + gxw;
      const float* r2 = p2 + gy * IMGW + gxw;
      float4u A0 = *(const float4u*)(r1);
      float4u A1 = *(const float4u*)(r1 + 4);
      float4u A2 = *(const float4u*)(r1 + 8);
      float2u A3 = *(const float2u*)(r1 + 12);
      float4u B0 = *(const float4u*)(r2);
      float4u B1 = *(const float4u*)(r2 + 4);
      float4u B2 = *(const float4u*)(r2 + 8);
      float2u B3 = *(const float2u*)(r2 + 12);
#pragma unroll
      for (int i = 0; i < 4; ++i) {
        av[i] = A0[i]; av[4 + i] = A1[i]; av[8 + i] = A2[i];
        bv[i] = B0[i]; bv[4 + i] = B1[i]; bv[8 + i] = B2[i];
      }
      av[12] = A3[0]; av[13] = A3[1];
      bv[12] = B3[0]; bv[13] = B3[1];
    } else {
      bool rowok = (gy >= 0) && (gy < IMGH);
      const float* r1 = p1 + gy * IMGW;
      const float* r2 = p2 + gy * IMGW;
#pragma unroll
      for (int i = 0; i < 14; ++i) {
        int gx = gxw + i;
        bool ok = rowok && (gx >= 0) && (gx < IMGW);
        av[i] = ok ? r1[gx] : 0.0f;
        bv[i] = ok ? r2[gx] : 0.0f;
      }
    }
    float pv[14], mv[14];
#pragma unroll
    for (int k = 0; k < 14; ++k) {
      float p = av[k] + bv[k];
      float m = av[k] - bv[k];
      pv[k] = p * p;
      mv[k] = m * m;
    }
    float sa[4], sb[4], sp[4], sm[4];
#pragma unroll
    for (int o = 0; o < 4; ++o) {
      float ta = 0.f, tb = 0.f, tp = 0.f, tm = 0.f;
#pragma unroll
      for (int k = 0; k < 11; ++k) {
        float w = g[k];
        ta = fmaf(w, av[o + k], ta);
        tb = fmaf(w, bv[o + k], tb);
        tp = fmaf(w, pv[o + k], tp);
        tm = fmaf(w, mv[o + k], tm);
      }
      sa[o] = ta; sb[o] = tb; sp[o] = tp; sm[o] = tm;
    }
    uint4 wab, wpm;
    wab.x = pkbf(sa[0], sb[0]); wab.y = pkbf(sa[1], sb[1]);
    wab.z = pkbf(sa[2], sb[2]); wab.w = pkbf(sa[3], sb[3]);
    wpm.x = pkbf(sp[0], sm[0]); wpm.y = pkbf(sp[1], sm[1]);
    wpm.z = pkbf(sp[2], sm[2]); wpm.w = pkbf(sp[3], sm[3]);
    *(uint4*)&hAB[r][c0] = wab;
    *(uint4*)&hPM[r][c0] = wpm;
  }
  __syncthreads();

  // ---- Stage 3: vertical pass in registers, 8 output rows per thread ----
  const int c = tid & 31;
  const int r0 = (tid >> 5) << 3;  // 0..56
  float mu1[8], mu2[8], qp[8], qm[8];
  {
    float m1[18], m2[18];
#pragma unroll
    for (int k = 0; k < 18; ++k) {
      uint32_t w = hAB[r0 + k][c];
      m1[k] = up_lo(w);
      m2[k] = up_hi(w);
    }
#pragma unroll
    for (int o = 0; o < 8; ++o) {
      float s = 0.f, t = 0.f;
#pragma unroll
      for (int k = 0; k < 11; ++k) {
        s = fmaf(g[k], m1[o + k], s);
        t = fmaf(g[k], m2[o + k], t);
      }
      mu1[o] = s; mu2[o] = t;
    }
#pragma unroll
    for (int k = 0; k < 18; ++k) {
      uint32_t w = hPM[r0 + k][c];
      m1[k] = up_lo(w);
      m2[k] = up_hi(w);
    }
#pragma unroll
    for (int o = 0; o < 8; ++o) {
      float s = 0.f, t = 0.f;
#pragma unroll
      for (int k = 0; k < 11; ++k) {
        s = fmaf(g[k], m1[o + k], s);
        t = fmaf(g[k], m2[o + k], t);
      }
      qp[o] = s; qm[o] = t;
    }
  }

  float ssum = 0.f;
#pragma unroll
  for (int o = 0; o < 8; ++o) {
    float m1 = mu1[o], m2 = mu2[o];
    float sumsq = 0.5f * (qp[o] + qm[o]);   // E[a^2] + E[b^2]
    float eab = 0.25f * (qp[o] - qm[o]);    // E[ab]
    float m1s = m1 * m1, m2s = m2 * m2, m12 = m1 * m2;
    float sg12 = eab - m12;
    float sgsum = sumsq - m1s - m2s;        // sigma1 + sigma2
    float num = (2.0f * m12 + C1v) * (2.0f * sg12 + C2v);
    float den = (m1s + m2s + C1v) * (sgsum + C2v);
    float r = num * __builtin_amdgcn_rcpf(den);
    // Guard singular pixels (den rounds to +-0 -> inf; mixed-sign infs -> NaN).
    if (!__builtin_isfinite(r)) r = 0.0f;
    ssum += r;
  }

  // ---- block reduction (deterministic) ----
#pragma unroll
  for (int off = 32; off > 0; off >>= 1) ssum += __shfl_down(ssum, off, 64);
  if ((tid & 63) == 0) sWave[tid >> 6] = ssum;
  __syncthreads();
  if (tid == 0) {
    partial[(blockIdx.z * NBY + blockIdx.y) * NBX + blockIdx.x] =
        sWave[0] + sWave[1] + sWave[2] + sWave[3];
  }
}

__global__ __launch_bounds__(256) void ssim_reduce(
    const float* __restrict__ partial, float* __restrict__ out) {
  const int tid = threadIdx.x;
  float s = 0.f;
  for (int i = tid; i < NBLOCKS; i += 256) s += partial[i];
#pragma unroll
  for (int off = 32; off > 0; off >>= 1) s += __shfl_down(s, off, 64);
  __shared__ float sw[4];
  if ((tid & 63) == 0) sw[tid >> 6] = s;
  __syncthreads();
  if (tid == 0) {
    float tot = sw[0] + sw[1] + sw[2] + sw[3];
    // mean((1 - ssim)/2) = 0.5 * (1 - mean(ssim))
    float val = 0.5f * (1.0f - tot * (1.0f / (32.0f * 512.0f * 512.0f)));
    if (!__builtin_isfinite(val)) val = 0.0f;
    out[0] = val;
  }
}

extern "C" void kernel_launch(void* const* d_in, const int* in_sizes, int n_in,
                              void* d_out, int out_size, void* d_ws,
                              size_t ws_size, hipStream_t stream) {
  const float* img1 = (const float*)d_in[0];
  const float* img2 = (const float*)d_in[1];
  float* partial = (float*)d_ws;  // 4096 floats = 16 KB
  float* out = (float*)d_out;

  dim3 grid(NBX, NBY, NIMG);
  hipLaunchKernelGGL(ssim_main, grid, dim3(256), 0, stream, img1, img2,
                     partial);
  hipLaunchKernelGGL(ssim_reduce, dim3(1), dim3(256), 0, stream, partial, out);
}

// Round 7
// 54.656 us; speedup vs baseline: 1.5484x; 1.3542x over previous
//
#include <hip/hip_runtime.h>

// SSIM loss, fused separable 11x11 Gaussian conv + SSIM map + mean.
// Images: 32 x 1 x 512 x 512 fp32. Output: 1 fp32 scalar.
//
// R7 = R6 + raw-tile LDS staging engineered for HBM-latency batching.
// Theory: stage-2 window loads were cold HBM misses (~900cy) issued in
// 2-3 serialized rounds per wave -> VALUBusy capped ~40%. Now all staging
// loads issue back-to-back (one latency exposure), and stage 2 reads
// windows from LDS via aligned b128/b64 (balanced banks, hidden).
//
// Stage 0: global -> LDS raw tiles (74x44 dwords/img, zero-padded borders)
// Stage 2: horizontal Gaussian on {a,b,p^2,m^2} from LDS -> packed bf16 LDS
//   (4-field algebra: p=a+b, m=a-b; E[a2]+E[b2]=(cp+cm)/2, E[ab]=(cp-cm)/4)
// Stage 3: vertical Gaussian in registers -> SSIM -> block partial sum
// Kernel 2: deterministic tree reduce of 4096 partials -> scalar.

#define IMGW 512
#define IMGH 512
#define NIMG 32
#define TW 32
#define TH 64
#define IN_H 74        // TH + 10
#define IN_W 44        // LDS row stride (dwords); cols 0..41 used, 42..43 pad
#define NCHUNK (IN_H * 11)   // 814 16B chunks per image tile
#define NBX 16         // 512 / TW
#define NBY 8          // 512 / TH
#define NBLOCKS (NBX * NBY * NIMG)   // 4096

typedef float float4a __attribute__((ext_vector_type(4)));              // 16B align
typedef float float2a __attribute__((ext_vector_type(2)));              // 8B align

__device__ __forceinline__ uint32_t pkbf(float lo, float hi) {
  uint32_t a = __builtin_bit_cast(uint32_t, lo);
  uint32_t b = __builtin_bit_cast(uint32_t, hi);
  return (a >> 16) | (b & 0xffff0000u);
}
__device__ __forceinline__ float up_lo(uint32_t w) {
  return __builtin_bit_cast(float, w << 16);
}
__device__ __forceinline__ float up_hi(uint32_t w) {
  return __builtin_bit_cast(float, w & 0xffff0000u);
}

__global__ __launch_bounds__(256, 3) void ssim_main(
    const float* __restrict__ img1, const float* __restrict__ img2,
    float* __restrict__ partial) {
  __shared__ float4a sA4[IN_H * 11];   // raw img1 tile, 13.0 KB
  __shared__ float4a sB4[IN_H * 11];   // raw img2 tile, 13.0 KB
  __shared__ uint32_t hAB[IN_H][TW];   // (conv a, conv b)   9.25 KB
  __shared__ uint32_t hPM[IN_H][TW];   // (conv p^2, conv m^2) 9.25 KB
  __shared__ float sWave[4];
  float* sA = (float*)sA4;
  float* sB = (float*)sB4;

  // Unnormalized Gaussian, 2*sigma^2 = 4 (faithful to reference).
  constexpr float g[11] = {0.0019304541f, 0.018315639f, 0.10539922f,
                           0.36787944f,   0.7788008f,   1.0f,
                           0.7788008f,    0.36787944f,  0.10539922f,
                           0.018315639f,  0.0019304541f};
  constexpr float C1v = 6.5025f;    // (0.01*255)^2
  constexpr float C2v = 58.5225f;   // (0.03*255)^2

  const int tid = threadIdx.x;
  const int bx = blockIdx.x;
  const int by = blockIdx.y;
  const int x0 = bx * TW - 5;
  const int y0 = by * TH - 5;
  const float* __restrict__ p1 = img1 + (size_t)blockIdx.z * (IMGW * IMGH);
  const float* __restrict__ p2 = img2 + (size_t)blockIdx.z * (IMGW * IMGH);

  // ---- Stage 0: stage raw tiles; all global loads issued back-to-back ----
  {
    float4a va[4], vb[4];
    int dst[4];
#pragma unroll
    for (int i = 0; i < 4; ++i) {
      int ch = tid + 256 * i;
      bool live = (ch < NCHUNK);
      int r = live ? (ch / 11) : 0;
      int cg = ch - r * 11;
      int gy = y0 + r;
      int gx = x0 + 4 * cg;
      dst[i] = live ? (ch * 4) : -1;     // LDS dword addr == r*44 + 4*cg
      bool rowok = live && (gy >= 0) && (gy < IMGH);
      if (rowok && gx >= 0 && gx + 3 < IMGW) {
        const float* q1 = p1 + gy * IMGW + gx;
        const float* q2 = p2 + gy * IMGW + gx;
        va[i] = *(const float4a*)q1;
        vb[i] = *(const float4a*)q2;
      } else {
#pragma unroll
        for (int j = 0; j < 4; ++j) {
          int xx = gx + j;
          bool ok = rowok && (xx >= 0) && (xx < IMGW);
          int off = gy * IMGW + xx;
          va[i][j] = ok ? p1[off] : 0.0f;
          vb[i][j] = ok ? p2[off] : 0.0f;
        }
      }
    }
#pragma unroll
    for (int i = 0; i < 4; ++i) {
      if (dst[i] >= 0) {
        *(float4a*)&sA[dst[i]] = va[i];
        *(float4a*)&sB[dst[i]] = vb[i];
      }
    }
  }
  __syncthreads();

  // ---- Stage 2: horizontal pass from LDS, 4 outputs/task ----
  // tasks: 74 rows x 8 col-groups = 592
  for (int idx = tid; idx < IN_H * (TW / 4); idx += 256) {
    int r = idx >> 3;
    int c0 = (idx & 7) << 2;
    int base = r * IN_W + c0;   // 16B-aligned (c0 % 4 == 0)
    float av[14], bv[14];
    {
      float4a a0 = *(const float4a*)&sA[base];
      float4a a1 = *(const float4a*)&sA[base + 4];
      float4a a2 = *(const float4a*)&sA[base + 8];
      float2a a3 = *(const float2a*)&sA[base + 12];
      float4a b0 = *(const float4a*)&sB[base];
      float4a b1 = *(const float4a*)&sB[base + 4];
      float4a b2 = *(const float4a*)&sB[base + 8];
      float2a b3 = *(const float2a*)&sB[base + 12];
#pragma unroll
      for (int i = 0; i < 4; ++i) {
        av[i] = a0[i]; av[4 + i] = a1[i]; av[8 + i] = a2[i];
        bv[i] = b0[i]; bv[4 + i] = b1[i]; bv[8 + i] = b2[i];
      }
      av[12] = a3[0]; av[13] = a3[1];
      bv[12] = b3[0]; bv[13] = b3[1];
    }
    float pv[14], mv[14];
#pragma unroll
    for (int k = 0; k < 14; ++k) {
      float p = av[k] + bv[k];
      float m = av[k] - bv[k];
      pv[k] = p * p;
      mv[k] = m * m;
    }
    float sa[4], sb[4], sp[4], sm[4];
#pragma unroll
    for (int o = 0; o < 4; ++o) {
      float ta = 0.f, tb = 0.f, tp = 0.f, tm = 0.f;
#pragma unroll
      for (int k = 0; k < 11; ++k) {
        float w = g[k];
        ta = fmaf(w, av[o + k], ta);
        tb = fmaf(w, bv[o + k], tb);
        tp = fmaf(w, pv[o + k], tp);
        tm = fmaf(w, mv[o + k], tm);
      }
      sa[o] = ta; sb[o] = tb; sp[o] = tp; sm[o] = tm;
    }
    uint4 wab, wpm;
    wab.x = pkbf(sa[0], sb[0]); wab.y = pkbf(sa[1], sb[1]);
    wab.z = pkbf(sa[2], sb[2]); wab.w = pkbf(sa[3], sb[3]);
    wpm.x = pkbf(sp[0], sm[0]); wpm.y = pkbf(sp[1], sm[1]);
    wpm.z = pkbf(sp[2], sm[2]); wpm.w = pkbf(sp[3], sm[3]);
    *(uint4*)&hAB[r][c0] = wab;
    *(uint4*)&hPM[r][c0] = wpm;
  }
  __syncthreads();

  // ---- Stage 3: vertical pass in registers, 8 output rows per thread ----
  const int c = tid & 31;
  const int r0 = (tid >> 5) << 3;  // 0..56
  float mu1[8], mu2[8], qp[8], qm[8];
  {
    float m1[18], m2[18];
#pragma unroll
    for (int k = 0; k < 18; ++k) {
      uint32_t w = hAB[r0 + k][c];
      m1[k] = up_lo(w);
      m2[k] = up_hi(w);
    }
#pragma unroll
    for (int o = 0; o < 8; ++o) {
      float s = 0.f, t = 0.f;
#pragma unroll
      for (int k = 0; k < 11; ++k) {
        s = fmaf(g[k], m1[o + k], s);
        t = fmaf(g[k], m2[o + k], t);
      }
      mu1[o] = s; mu2[o] = t;
    }
#pragma unroll
    for (int k = 0; k < 18; ++k) {
      uint32_t w = hPM[r0 + k][c];
      m1[k] = up_lo(w);
      m2[k] = up_hi(w);
    }
#pragma unroll
    for (int o = 0; o < 8; ++o) {
      float s = 0.f, t = 0.f;
#pragma unroll
      for (int k = 0; k < 11; ++k) {
        s = fmaf(g[k], m1[o + k], s);
        t = fmaf(g[k], m2[o + k], t);
      }
      qp[o] = s; qm[o] = t;
    }
  }

  float ssum = 0.f;
#pragma unroll
  for (int o = 0; o < 8; ++o) {
    float m1 = mu1[o], m2 = mu2[o];
    float sumsq = 0.5f * (qp[o] + qm[o]);   // E[a^2] + E[b^2]
    float eab = 0.25f * (qp[o] - qm[o]);    // E[ab]
    float m1s = m1 * m1, m2s = m2 * m2, m12 = m1 * m2;
    float sg12 = eab - m12;
    float sgsum = sumsq - m1s - m2s;        // sigma1 + sigma2
    float num = (2.0f * m12 + C1v) * (2.0f * sg12 + C2v);
    float den = (m1s + m2s + C1v) * (sgsum + C2v);
    float r = num * __builtin_amdgcn_rcpf(den);
    // Guard singular pixels (den rounds to +-0 -> inf; mixed-sign infs -> NaN).
    if (!__builtin_isfinite(r)) r = 0.0f;
    ssum += r;
  }

  // ---- block reduction (deterministic) ----
#pragma unroll
  for (int off = 32; off > 0; off >>= 1) ssum += __shfl_down(ssum, off, 64);
  if ((tid & 63) == 0) sWave[tid >> 6] = ssum;
  __syncthreads();
  if (tid == 0) {
    partial[(blockIdx.z * NBY + blockIdx.y) * NBX + blockIdx.x] =
        sWave[0] + sWave[1] + sWave[2] + sWave[3];
  }
}

__global__ __launch_bounds__(256) void ssim_reduce(
    const float* __restrict__ partial, float* __restrict__ out) {
  const int tid = threadIdx.x;
  float s = 0.f;
  for (int i = tid; i < NBLOCKS; i += 256) s += partial[i];
#pragma unroll
  for (int off = 32; off > 0; off >>= 1) s += __shfl_down(s, off, 64);
  __shared__ float sw[4];
  if ((tid & 63) == 0) sw[tid >> 6] = s;
  __syncthreads();
  if (tid == 0) {
    float tot = sw[0] + sw[1] + sw[2] + sw[3];
    // mean((1 - ssim)/2) = 0.5 * (1 - mean(ssim))
    float val = 0.5f * (1.0f - tot * (1.0f / (32.0f * 512.0f * 512.0f)));
    if (!__builtin_isfinite(val)) val = 0.0f;
    out[0] = val;
  }
}

extern "C" void kernel_launch(void* const* d_in, const int* in_sizes, int n_in,
                              void* d_out, int out_size, void* d_ws,
                              size_t ws_size, hipStream_t stream) {
  const float* img1 = (const float*)d_in[0];
  const float* img2 = (const float*)d_in[1];
  float* partial = (float*)d_ws;  // 4096 floats = 16 KB
  float* out = (float*)d_out;

  dim3 grid(NBX, NBY, NIMG);
  hipLaunchKernelGGL(ssim_main, grid, dim3(256), 0, stream, img1, img2,
                     partial);
  hipLaunchKernelGGL(ssim_reduce, dim3(1), dim3(256), 0, stream, partial, out);
}